// Round 2
// baseline (415.770 us; speedup 1.0000x reference)
//
#include <hip/hip_runtime.h>

#define SHIFT 4

typedef __bf16 bf16x8 __attribute__((ext_vector_type(8)));
typedef float  f32x4  __attribute__((ext_vector_type(4)));

__device__ __forceinline__ ushort f2bf(float f) {
  union { float f; unsigned u; } c; c.f = f;
  unsigned r = c.u + 0x7FFFu + ((c.u >> 16) & 1u);
  return (ushort)(r >> 16);
}

// Padded LDS leading dims (all ×2B multiples of 16B, chosen so stride%128B
// spreads a 16-lane ds_read_b128 column access over >=16 banks; G4).
#define LDQ 40   // q/k tiles: [3][64][LDQ]
#define LDV 72   // v transposed: [3][32][LDV]
#define LDA 104  // h / attn-out / mlp row tiles: [rows][LDA]
#define LDW 104  // transposed weight tiles: [96][LDW]
#define LDP 72   // P scratch: [64][LDP]

// ---------------------------------------------------------------------------
// Kernel 1: LN1 + shift + window partition + windowed MHSA + proj + residual.
// One block = one 8x8 window (64 tokens). 256 threads = 4 waves; wave w owns
// output rows 16w..16w+15 of every GEMM (MFMA 16x16x32 bf16).
// ---------------------------------------------------------------------------
__global__ __launch_bounds__(256, 2)
void swin_attn_kernel(const float* __restrict__ x,
                      const float* __restrict__ ln1g, const float* __restrict__ ln1b,
                      const float* __restrict__ qkvw, const float* __restrict__ qkvb,
                      const float* __restrict__ projw, const float* __restrict__ btab,
                      float* __restrict__ out)
{
  __shared__ ushort q_s[3][64][LDQ];             // 15360 B  (q, pre-scaled)
  __shared__ ushort k_s[3][64][LDQ];             // 15360 B
  __shared__ ushort v_s[3][32][LDV];             // 13824 B  (v transposed [dim][tok])
  __shared__ ushort h_s[64][LDA];                // 13312 B  (LN'd h, later attn-out)
  __shared__ __align__(16) char uni[96 * LDW * 2]; // 19968 B union:
  ushort* w_s    = (ushort*)uni;                 //   weight chunk [96][LDW]
  ushort* p_s    = (ushort*)uni;                 //   P scratch [64][LDP] = 9216 B
  float*  bias_s = (float*)(uni + 9216);         //   rel-pos bias table (675 f32)

  const int tid  = threadIdx.x;
  const int lane = tid & 63;
  const int wv   = tid >> 6;
  const int l15  = lane & 15;
  const int g4   = lane >> 4;
  const int blk  = blockIdx.x;          // b*256 + wy*16 + wx
  const int b    = blk >> 8;
  const int wy   = (blk >> 4) & 15;
  const int wx   = blk & 15;

  // ---------------- Phase 1: LayerNorm (4 lanes per token) ----------------
  {
    const int t = tid >> 2, p = tid & 3;
    const int ti = t >> 3, tj = t & 7;
    const int iy = (wy * 8 + ti + SHIFT) & 127;   // shifted-image -> source pixel
    const int ix = (wx * 8 + tj + SHIFT) & 127;
    const float* rowp = x + ((size_t)(b * 16384 + iy * 128 + ix)) * 96 + p * 24;
    float vb[24];
    float s = 0.f, ss = 0.f;
#pragma unroll
    for (int u = 0; u < 6; ++u) {
      f32x4 f = *(const f32x4*)(rowp + 4 * u);
#pragma unroll
      for (int e = 0; e < 4; ++e) { float q = f[e]; vb[4*u+e] = q; s += q; ss += q*q; }
    }
    s  += __shfl_xor(s, 1);  s  += __shfl_xor(s, 2);
    ss += __shfl_xor(ss, 1); ss += __shfl_xor(ss, 2);
    const float mean = s * (1.f / 96.f);
    const float var  = ss * (1.f / 96.f) - mean * mean;
    const float rstd = rsqrtf(var + 1e-5f);
#pragma unroll
    for (int u = 0; u < 6; ++u) {
      f32x4 gg = *(const f32x4*)(ln1g + p * 24 + 4 * u);
      f32x4 bb = *(const f32x4*)(ln1b + p * 24 + 4 * u);
      ushort r0 = f2bf((vb[4*u+0] - mean) * rstd * gg[0] + bb[0]);
      ushort r1 = f2bf((vb[4*u+1] - mean) * rstd * gg[1] + bb[1]);
      ushort r2 = f2bf((vb[4*u+2] - mean) * rstd * gg[2] + bb[2]);
      ushort r3 = f2bf((vb[4*u+3] - mean) * rstd * gg[3] + bb[3]);
      *(uint*)&h_s[t][p*24 + 4*u + 0] = (uint)r0 | ((uint)r1 << 16);
      *(uint*)&h_s[t][p*24 + 4*u + 2] = (uint)r2 | ((uint)r3 << 16);
    }
  }
  __syncthreads();

  // ---------------- Phase 2: QKV projection (3 chunks of 96 cols) ----------
  const float qscale = 0.17677669529663687f;  // 1/sqrt(32)
  for (int c = 0; c < 3; ++c) {
    for (int n = tid; n < 96 * 96; n += 256) {          // stage W^T chunk (bf16)
      const int kk = n / 96, col = n - kk * 96;
      w_s[col * LDW + kk] = f2bf(qkvw[kk * 288 + c * 96 + col]);
    }
    __syncthreads();
    f32x4 acc[6];
#pragma unroll
    for (int t = 0; t < 6; ++t) {
      const float bv = qkvb[c * 96 + t * 16 + l15];
      f32x4 a4 = {bv, bv, bv, bv};
      acc[t] = a4;
    }
#pragma unroll
    for (int ks = 0; ks < 3; ++ks) {
      bf16x8 a = *(const bf16x8*)&h_s[16 * wv + l15][ks * 32 + 8 * g4];
#pragma unroll
      for (int t = 0; t < 6; ++t) {
        bf16x8 bb = *(const bf16x8*)&w_s[(t * 16 + l15) * LDW + ks * 32 + 8 * g4];
        acc[t] = __builtin_amdgcn_mfma_f32_16x16x32_bf16(a, bb, acc[t], 0, 0, 0);
      }
    }
    // scatter results: D layout col = l15(+16t), row = 16wv + 4*g4 + reg
    if (c < 2) {
      const float sc = (c == 0) ? qscale : 1.f;
#pragma unroll
      for (int t = 0; t < 6; ++t) {
        const int head = t >> 1, dim = (t & 1) * 16 + l15;
#pragma unroll
        for (int r = 0; r < 4; ++r) {
          const int tok = 16 * wv + 4 * g4 + r;
          if (c == 0) q_s[head][tok][dim] = f2bf(acc[t][r] * sc);
          else        k_s[head][tok][dim] = f2bf(acc[t][r]);
        }
      }
    } else {  // v: store transposed [head][dim][tok], 4 regs = 4 consecutive toks
#pragma unroll
      for (int t = 0; t < 6; ++t) {
        const int head = t >> 1, dim = (t & 1) * 16 + l15;
        uint2 pk;
        pk.x = (uint)f2bf(acc[t][0]) | ((uint)f2bf(acc[t][1]) << 16);
        pk.y = (uint)f2bf(acc[t][2]) | ((uint)f2bf(acc[t][3]) << 16);
        *(uint2*)&v_s[head][dim][16 * wv + 4 * g4] = pk;
      }
    }
    __syncthreads();
  }

  // stage rel-pos bias table (union region now free)
  for (int n = tid; n < 675; n += 256) bias_s[n] = btab[n];
  __syncthreads();

  // ---------------- Phase 3: attention, head by head ----------------
  const int rowb = 16 * wv;
  int qry[4], qrx[4];
#pragma unroll
  for (int r = 0; r < 4; ++r) {   // shift-mask region ids of this lane's q rows
    const int row = rowb + 4 * g4 + r;
    const int ti2 = row >> 3, tj2 = row & 7;
    qry[r] = (wy == 15) ? (ti2 < 4 ? 1 : 2) : 0;
    qrx[r] = (wx == 15) ? (tj2 < 4 ? 1 : 2) : 0;
  }
  const f32x4 zf = {0.f, 0.f, 0.f, 0.f};
  for (int h = 0; h < 3; ++h) {
    bf16x8 aq = *(const bf16x8*)&q_s[h][rowb + l15][8 * g4];
    f32x4 sc[4];
#pragma unroll
    for (int n = 0; n < 4; ++n) {
      bf16x8 bk = *(const bf16x8*)&k_s[h][n * 16 + l15][8 * g4];
      sc[n] = __builtin_amdgcn_mfma_f32_16x16x32_bf16(aq, bk, zf, 0, 0, 0);
    }
    // bias + shift-window mask
#pragma unroll
    for (int n = 0; n < 4; ++n) {
      const int colt = n * 16 + l15;
      const int ki = colt >> 3, kj = colt & 7;
      const int kry = (wy == 15) ? (ki < 4 ? 1 : 2) : 0;
      const int krx = (wx == 15) ? (kj < 4 ? 1 : 2) : 0;
#pragma unroll
      for (int r = 0; r < 4; ++r) {
        const int row = rowb + 4 * g4 + r;
        const int ti2 = row >> 3, tj2 = row & 7;
        const float bv = bias_s[((ti2 - ki + 7) * 15 + (tj2 - kj + 7)) * 3 + h];
        const float mk = (qry[r] == kry && qrx[r] == krx) ? 0.f : -100.f;
        sc[n][r] += bv + mk;
      }
    }
    // wave-parallel softmax: row r lives in one 16-lane group x 4 tiles
    float mx[4], sm[4];
#pragma unroll
    for (int r = 0; r < 4; ++r) {
      float m = fmaxf(fmaxf(sc[0][r], sc[1][r]), fmaxf(sc[2][r], sc[3][r]));
      m = fmaxf(m, __shfl_xor(m, 1)); m = fmaxf(m, __shfl_xor(m, 2));
      m = fmaxf(m, __shfl_xor(m, 4)); m = fmaxf(m, __shfl_xor(m, 8));
      mx[r] = m; sm[r] = 0.f;
    }
#pragma unroll
    for (int n = 0; n < 4; ++n)
#pragma unroll
      for (int r = 0; r < 4; ++r) {
        float p = __expf(sc[n][r] - mx[r]); sc[n][r] = p; sm[r] += p;
      }
#pragma unroll
    for (int r = 0; r < 4; ++r) {
      float s2 = sm[r];
      s2 += __shfl_xor(s2, 1); s2 += __shfl_xor(s2, 2);
      s2 += __shfl_xor(s2, 4); s2 += __shfl_xor(s2, 8);
      sm[r] = 1.f / s2;
    }
    // P -> LDS (wave-local rows only; no barrier needed)
#pragma unroll
    for (int n = 0; n < 4; ++n)
#pragma unroll
      for (int r = 0; r < 4; ++r)
        p_s[(rowb + 4 * g4 + r) * LDP + n * 16 + l15] = f2bf(sc[n][r]);
    // PV
    f32x4 ov[2] = {zf, zf};
#pragma unroll
    for (int ks = 0; ks < 2; ++ks) {
      bf16x8 pa = *(const bf16x8*)&p_s[(rowb + l15) * LDP + ks * 32 + 8 * g4];
#pragma unroll
      for (int t2 = 0; t2 < 2; ++t2) {
        bf16x8 vb2 = *(const bf16x8*)&v_s[h][t2 * 16 + l15][ks * 32 + 8 * g4];
        ov[t2] = __builtin_amdgcn_mfma_f32_16x16x32_bf16(pa, vb2, ov[t2], 0, 0, 0);
      }
    }
#pragma unroll
    for (int t2 = 0; t2 < 2; ++t2)
#pragma unroll
      for (int r = 0; r < 4; ++r)
        h_s[rowb + 4 * g4 + r][h * 32 + t2 * 16 + l15] = f2bf(ov[t2][r] * sm[r]);
  }
  __syncthreads();

  // ---------------- Phase 4: output projection ----------------
  for (int n = tid; n < 96 * 96; n += 256) {
    const int kk = n / 96, col = n - kk * 96;
    w_s[col * LDW + kk] = f2bf(projw[kk * 96 + col]);
  }
  __syncthreads();
  f32x4 po[6];
#pragma unroll
  for (int t = 0; t < 6; ++t) po[t] = zf;
#pragma unroll
  for (int ks = 0; ks < 3; ++ks) {
    bf16x8 a = *(const bf16x8*)&h_s[rowb + l15][ks * 32 + 8 * g4];
#pragma unroll
    for (int t = 0; t < 6; ++t) {
      bf16x8 bb = *(const bf16x8*)&w_s[(t * 16 + l15) * LDW + ks * 32 + 8 * g4];
      po[t] = __builtin_amdgcn_mfma_f32_16x16x32_bf16(a, bb, po[t], 0, 0, 0);
    }
  }
  // epilogue: window reverse + unshift + residual (re-read x)
#pragma unroll
  for (int r = 0; r < 4; ++r) {
    const int row = rowb + 4 * g4 + r;
    const int ti2 = row >> 3, tj2 = row & 7;
    const int iy = (wy * 8 + ti2 + SHIFT) & 127;
    const int ix = (wx * 8 + tj2 + SHIFT) & 127;
    const size_t gbase = ((size_t)(b * 16384 + iy * 128 + ix)) * 96;
#pragma unroll
    for (int t = 0; t < 6; ++t) {
      const size_t gi = gbase + t * 16 + l15;
      out[gi] = x[gi] + po[t][r];
    }
  }
}

// ---------------------------------------------------------------------------
// Kernel 2: LN2 + MLP(4x, gelu-tanh) + residual, in place on d_out.
// 512 threads = 8 waves, 128 rows per block; each row owned by one wave.
// ---------------------------------------------------------------------------
__global__ __launch_bounds__(512, 2)
void swin_mlp_kernel(const float* __restrict__ ln2g, const float* __restrict__ ln2b,
                     const float* __restrict__ w1, const float* __restrict__ w2,
                     float* xm)
{
  __shared__ ushort h_s[128][LDA];   // 26624 B
  __shared__ ushort w1_s[96][LDW];   // 19968 B
  __shared__ ushort w2_s[96][LDW];   // 19968 B
  __shared__ ushort u_s[128][LDA];   // 26624 B

  const int tid = threadIdx.x, lane = tid & 63, wv = tid >> 6;
  const int l15 = lane & 15, g4 = lane >> 4;
  const size_t rowg = (size_t)blockIdx.x * 128;

  // LN2 (4 lanes per row)
  {
    const int t = tid >> 2, p = tid & 3;
    const float* rowp = xm + (rowg + t) * 96 + p * 24;
    float vb[24];
    float s = 0.f, ss = 0.f;
#pragma unroll
    for (int u = 0; u < 6; ++u) {
      f32x4 f = *(const f32x4*)(rowp + 4 * u);
#pragma unroll
      for (int e = 0; e < 4; ++e) { float q = f[e]; vb[4*u+e] = q; s += q; ss += q*q; }
    }
    s  += __shfl_xor(s, 1);  s  += __shfl_xor(s, 2);
    ss += __shfl_xor(ss, 1); ss += __shfl_xor(ss, 2);
    const float mean = s * (1.f / 96.f);
    const float var  = ss * (1.f / 96.f) - mean * mean;
    const float rstd = rsqrtf(var + 1e-5f);
#pragma unroll
    for (int u = 0; u < 6; ++u) {
      f32x4 gg = *(const f32x4*)(ln2g + p * 24 + 4 * u);
      f32x4 bb = *(const f32x4*)(ln2b + p * 24 + 4 * u);
      ushort r0 = f2bf((vb[4*u+0] - mean) * rstd * gg[0] + bb[0]);
      ushort r1 = f2bf((vb[4*u+1] - mean) * rstd * gg[1] + bb[1]);
      ushort r2 = f2bf((vb[4*u+2] - mean) * rstd * gg[2] + bb[2]);
      ushort r3 = f2bf((vb[4*u+3] - mean) * rstd * gg[3] + bb[3]);
      *(uint*)&h_s[t][p*24 + 4*u + 0] = (uint)r0 | ((uint)r1 << 16);
      *(uint*)&h_s[t][p*24 + 4*u + 2] = (uint)r2 | ((uint)r3 << 16);
    }
  }
  __syncthreads();

  const int rowb = 16 * wv;
  const f32x4 zf = {0.f, 0.f, 0.f, 0.f};
  f32x4 acc[6];
#pragma unroll
  for (int t = 0; t < 6; ++t) acc[t] = zf;

  for (int c = 0; c < 4; ++c) {   // 4 chunks of 96 hidden cols
    for (int n = tid; n < 9216; n += 512) {
      const int kk = n / 96, col = n - kk * 96;
      w1_s[col][kk] = f2bf(w1[kk * 384 + c * 96 + col]);        // w1^T chunk
      w2_s[col][kk] = f2bf(w2[(c * 96 + kk) * 96 + col]);       // w2 chunk^T
    }
    __syncthreads();
    f32x4 ua[6];
#pragma unroll
    for (int t = 0; t < 6; ++t) ua[t] = zf;
#pragma unroll
    for (int ks = 0; ks < 3; ++ks) {
      bf16x8 a = *(const bf16x8*)&h_s[rowb + l15][ks * 32 + 8 * g4];
#pragma unroll
      for (int t = 0; t < 6; ++t) {
        bf16x8 bb = *(const bf16x8*)&w1_s[t * 16 + l15][ks * 32 + 8 * g4];
        ua[t] = __builtin_amdgcn_mfma_f32_16x16x32_bf16(a, bb, ua[t], 0, 0, 0);
      }
    }
    // gelu (tanh approx, JAX default) -> u_s (wave-local rows)
#pragma unroll
    for (int t = 0; t < 6; ++t)
#pragma unroll
      for (int r = 0; r < 4; ++r) {
        const float v = ua[t][r];
        const float a3 = 0.7978845608028654f * (v + 0.044715f * v * v * v);
        const float e = __expf(2.f * a3);
        const float th = 1.f - 2.f / (e + 1.f);
        u_s[rowb + 4 * g4 + r][t * 16 + l15] = f2bf(0.5f * v * (1.f + th));
      }
#pragma unroll
    for (int ks = 0; ks < 3; ++ks) {
      bf16x8 pa = *(const bf16x8*)&u_s[rowb + l15][ks * 32 + 8 * g4];
#pragma unroll
      for (int t = 0; t < 6; ++t) {
        bf16x8 bb = *(const bf16x8*)&w2_s[t * 16 + l15][ks * 32 + 8 * g4];
        acc[t] = __builtin_amdgcn_mfma_f32_16x16x32_bf16(pa, bb, acc[t], 0, 0, 0);
      }
    }
    __syncthreads();
  }
  // epilogue: residual, in place (rows owned by this wave only)
#pragma unroll
  for (int r = 0; r < 4; ++r) {
    const size_t gr = (rowg + rowb + 4 * g4 + r) * 96;
#pragma unroll
    for (int t = 0; t < 6; ++t) {
      const size_t gi = gr + t * 16 + l15;
      xm[gi] = xm[gi] + acc[t][r];
    }
  }
}

extern "C" void kernel_launch(void* const* d_in, const int* in_sizes, int n_in,
                              void* d_out, int out_size, void* d_ws, size_t ws_size,
                              hipStream_t stream) {
  (void)in_sizes; (void)n_in; (void)out_size; (void)d_ws; (void)ws_size;
  const float* x     = (const float*)d_in[0];
  const float* ln1g  = (const float*)d_in[1];
  const float* ln1b  = (const float*)d_in[2];
  const float* qkvw  = (const float*)d_in[3];
  const float* qkvb  = (const float*)d_in[4];
  const float* projw = (const float*)d_in[5];
  const float* btab  = (const float*)d_in[6];
  const float* ln2g  = (const float*)d_in[7];
  const float* ln2b  = (const float*)d_in[8];
  const float* w1    = (const float*)d_in[9];
  const float* w2    = (const float*)d_in[10];
  float* out = (float*)d_out;

  swin_attn_kernel<<<4096, 256, 0, stream>>>(x, ln1g, ln1b, qkvw, qkvb, projw, btab, out);
  swin_mlp_kernel<<<2048, 512, 0, stream>>>(ln2g, ln2b, w1, w2, out);
}

// Round 3
// 260.884 us; speedup vs baseline: 1.5937x; 1.5937x over previous
//
#include <hip/hip_runtime.h>

#define SHIFT 4

typedef __bf16 bf16x8 __attribute__((ext_vector_type(8)));
typedef float  f32x4  __attribute__((ext_vector_type(4)));

__device__ __forceinline__ ushort f2bf(float f) {
  union { float f; unsigned u; } c; c.f = f;
  unsigned r = c.u + 0x7FFFu + ((c.u >> 16) & 1u);
  return (ushort)(r >> 16);
}

// Padded LDS leading dims.
#define LDQ 40   // q/k tiles: [3][64][LDQ]
#define LDV 72   // v transposed: [3][32][LDV]
#define LDA 104  // h / attn-out / mlp row tiles: [rows][LDA]
#define LDW 104  // transposed weight tiles: [96][LDW]  (208 B rows, 16B-aligned)
#define LDP 72   // P scratch: [64][LDP]

// ws layout (bf16 elements):
//   qkvwT  [288][96] @ 0        (col-major of qkvw: qkvwT[col][k] = qkvw[k][col])
//   projwT [96][96]  @ 27648
//   w1T    [384][96] @ 36864
//   w2T    [96][384] @ 73728    (w2T[col][k] = w2[k][col])
#define WS_QKV  0
#define WS_PROJ 27648
#define WS_W1   36864
#define WS_W2   73728
#define WS_TOT  110592

// ---------------------------------------------------------------------------
// Kernel 0: weight prep — f32 -> bf16, transposed to B-fragment layout.
// ---------------------------------------------------------------------------
__global__ __launch_bounds__(256)
void swin_prep_kernel(const float* __restrict__ qkvw, const float* __restrict__ projw,
                      const float* __restrict__ w1, const float* __restrict__ w2,
                      ushort* __restrict__ ws)
{
  const int i = blockIdx.x * 256 + threadIdx.x;
  if (i < 27648) {                       // qkvwT
    const int col = i / 96, kk = i - col * 96;
    ws[i] = f2bf(qkvw[kk * 288 + col]);
  } else if (i < 36864) {                // projwT
    const int j = i - 27648; const int col = j / 96, kk = j - col * 96;
    ws[i] = f2bf(projw[kk * 96 + col]);
  } else if (i < 73728) {                // w1T
    const int j = i - 36864; const int col = j / 96, kk = j - col * 96;
    ws[i] = f2bf(w1[kk * 384 + col]);
  } else if (i < WS_TOT) {               // w2T
    const int j = i - 73728; const int col = j / 384, kk = j - col * 384;
    ws[i] = f2bf(w2[kk * 96 + col]);
  }
}

// ---------------------------------------------------------------------------
// Kernel 1: LN1 + shift + window partition + windowed MHSA + proj + residual.
// One block = one 8x8 window (64 tokens). 256 threads = 4 waves.
// ---------------------------------------------------------------------------
__global__ __launch_bounds__(256, 2)
void swin_attn_kernel(const float* __restrict__ x,
                      const float* __restrict__ ln1g, const float* __restrict__ ln1b,
                      const ushort* __restrict__ ws, const float* __restrict__ qkvb,
                      const float* __restrict__ btab,
                      float* __restrict__ out)
{
  __shared__ ushort q_s[3][64][LDQ];             // 15360 B
  __shared__ ushort k_s[3][64][LDQ];             // 15360 B
  __shared__ ushort v_s[3][32][LDV];             // 13824 B
  __shared__ ushort h_s[64][LDA];                // 13312 B
  __shared__ __align__(16) char uni[96 * LDW * 2]; // 19968 B union:
  ushort* w_s    = (ushort*)uni;                 //   weight chunk [96][LDW]
  ushort* p_s    = (ushort*)uni;                 //   P scratch [64][LDP] = 9216 B
  float*  bias_s = (float*)(uni + 9216);         //   rel-pos bias (675 f32)

  const int tid  = threadIdx.x;
  const int lane = tid & 63;
  const int wv   = tid >> 6;
  const int l15  = lane & 15;
  const int g4   = lane >> 4;
  const int blk  = blockIdx.x;          // b*256 + wy*16 + wx
  const int b    = blk >> 8;
  const int wy   = (blk >> 4) & 15;
  const int wx   = blk & 15;

  // ---------------- Phase 1: LayerNorm (4 lanes per token) ----------------
  {
    const int t = tid >> 2, p = tid & 3;
    const int ti = t >> 3, tj = t & 7;
    const int iy = (wy * 8 + ti + SHIFT) & 127;
    const int ix = (wx * 8 + tj + SHIFT) & 127;
    const float* rowp = x + ((size_t)(b * 16384 + iy * 128 + ix)) * 96 + p * 24;
    float vb[24];
    float s = 0.f, ss = 0.f;
#pragma unroll
    for (int u = 0; u < 6; ++u) {
      f32x4 f = *(const f32x4*)(rowp + 4 * u);
#pragma unroll
      for (int e = 0; e < 4; ++e) { float q = f[e]; vb[4*u+e] = q; s += q; ss += q*q; }
    }
    s  += __shfl_xor(s, 1);  s  += __shfl_xor(s, 2);
    ss += __shfl_xor(ss, 1); ss += __shfl_xor(ss, 2);
    const float mean = s * (1.f / 96.f);
    const float var  = ss * (1.f / 96.f) - mean * mean;
    const float rstd = rsqrtf(var + 1e-5f);
#pragma unroll
    for (int u = 0; u < 6; ++u) {
      f32x4 gg = *(const f32x4*)(ln1g + p * 24 + 4 * u);
      f32x4 bb = *(const f32x4*)(ln1b + p * 24 + 4 * u);
      ushort r0 = f2bf((vb[4*u+0] - mean) * rstd * gg[0] + bb[0]);
      ushort r1 = f2bf((vb[4*u+1] - mean) * rstd * gg[1] + bb[1]);
      ushort r2 = f2bf((vb[4*u+2] - mean) * rstd * gg[2] + bb[2]);
      ushort r3 = f2bf((vb[4*u+3] - mean) * rstd * gg[3] + bb[3]);
      *(uint*)&h_s[t][p*24 + 4*u + 0] = (uint)r0 | ((uint)r1 << 16);
      *(uint*)&h_s[t][p*24 + 4*u + 2] = (uint)r2 | ((uint)r3 << 16);
    }
  }
  __syncthreads();

  // ---------------- Phase 2: QKV projection (3 chunks of 96 cols) ----------
  const float qscale = 0.17677669529663687f;  // 1/sqrt(32)
  for (int c = 0; c < 3; ++c) {
    const ushort* wsrc = ws + WS_QKV + c * 9216;        // [96 cols][96 k] bf16
    for (int m = tid; m < 1152; m += 256) {             // 16B-chunk copy
      const int col = m / 12, kko = (m - col * 12) * 8;
      *(uint4*)&w_s[col * LDW + kko] = *(const uint4*)&wsrc[col * 96 + kko];
    }
    __syncthreads();
    f32x4 acc[6];
#pragma unroll
    for (int t = 0; t < 6; ++t) {
      const float bv = qkvb[c * 96 + t * 16 + l15];
      f32x4 a4 = {bv, bv, bv, bv};
      acc[t] = a4;
    }
#pragma unroll
    for (int ks = 0; ks < 3; ++ks) {
      bf16x8 a = *(const bf16x8*)&h_s[16 * wv + l15][ks * 32 + 8 * g4];
#pragma unroll
      for (int t = 0; t < 6; ++t) {
        bf16x8 bb = *(const bf16x8*)&w_s[(t * 16 + l15) * LDW + ks * 32 + 8 * g4];
        acc[t] = __builtin_amdgcn_mfma_f32_16x16x32_bf16(a, bb, acc[t], 0, 0, 0);
      }
    }
    // scatter: D col = l15(+16t), row = 16wv + 4*g4 + reg
    if (c < 2) {
#pragma unroll
      for (int t = 0; t < 6; ++t) {
        const int head = t >> 1, dim = (t & 1) * 16 + l15;
#pragma unroll
        for (int r = 0; r < 4; ++r) {
          const int tok = 16 * wv + 4 * g4 + r;
          if (c == 0) q_s[head][tok][dim] = f2bf(acc[t][r] * qscale);
          else        k_s[head][tok][dim] = f2bf(acc[t][r]);
        }
      }
    } else {  // v transposed [head][dim][tok]
#pragma unroll
      for (int t = 0; t < 6; ++t) {
        const int head = t >> 1, dim = (t & 1) * 16 + l15;
        uint2 pk;
        pk.x = (uint)f2bf(acc[t][0]) | ((uint)f2bf(acc[t][1]) << 16);
        pk.y = (uint)f2bf(acc[t][2]) | ((uint)f2bf(acc[t][3]) << 16);
        *(uint2*)&v_s[head][dim][16 * wv + 4 * g4] = pk;
      }
    }
    __syncthreads();
  }

  // stage rel-pos bias table (union region now free)
  for (int n = tid; n < 675; n += 256) bias_s[n] = btab[n];
  __syncthreads();

  // ---------------- Phase 3: attention, head by head ----------------
  const int rowb = 16 * wv;
  int qry[4], qrx[4];
#pragma unroll
  for (int r = 0; r < 4; ++r) {
    const int row = rowb + 4 * g4 + r;
    const int ti2 = row >> 3, tj2 = row & 7;
    qry[r] = (wy == 15) ? (ti2 < 4 ? 1 : 2) : 0;
    qrx[r] = (wx == 15) ? (tj2 < 4 ? 1 : 2) : 0;
  }
  const f32x4 zf = {0.f, 0.f, 0.f, 0.f};
  for (int h = 0; h < 3; ++h) {
    bf16x8 aq = *(const bf16x8*)&q_s[h][rowb + l15][8 * g4];
    f32x4 sc[4];
#pragma unroll
    for (int n = 0; n < 4; ++n) {
      bf16x8 bk = *(const bf16x8*)&k_s[h][n * 16 + l15][8 * g4];
      sc[n] = __builtin_amdgcn_mfma_f32_16x16x32_bf16(aq, bk, zf, 0, 0, 0);
    }
#pragma unroll
    for (int n = 0; n < 4; ++n) {
      const int colt = n * 16 + l15;
      const int ki = colt >> 3, kj = colt & 7;
      const int kry = (wy == 15) ? (ki < 4 ? 1 : 2) : 0;
      const int krx = (wx == 15) ? (kj < 4 ? 1 : 2) : 0;
#pragma unroll
      for (int r = 0; r < 4; ++r) {
        const int row = rowb + 4 * g4 + r;
        const int ti2 = row >> 3, tj2 = row & 7;
        const float bv = bias_s[((ti2 - ki + 7) * 15 + (tj2 - kj + 7)) * 3 + h];
        const float mk = (qry[r] == kry && qrx[r] == krx) ? 0.f : -100.f;
        sc[n][r] += bv + mk;
      }
    }
    float mx[4], sm[4];
#pragma unroll
    for (int r = 0; r < 4; ++r) {
      float m = fmaxf(fmaxf(sc[0][r], sc[1][r]), fmaxf(sc[2][r], sc[3][r]));
      m = fmaxf(m, __shfl_xor(m, 1)); m = fmaxf(m, __shfl_xor(m, 2));
      m = fmaxf(m, __shfl_xor(m, 4)); m = fmaxf(m, __shfl_xor(m, 8));
      mx[r] = m; sm[r] = 0.f;
    }
#pragma unroll
    for (int n = 0; n < 4; ++n)
#pragma unroll
      for (int r = 0; r < 4; ++r) {
        float p = __expf(sc[n][r] - mx[r]); sc[n][r] = p; sm[r] += p;
      }
#pragma unroll
    for (int r = 0; r < 4; ++r) {
      float s2 = sm[r];
      s2 += __shfl_xor(s2, 1); s2 += __shfl_xor(s2, 2);
      s2 += __shfl_xor(s2, 4); s2 += __shfl_xor(s2, 8);
      sm[r] = 1.f / s2;
    }
#pragma unroll
    for (int n = 0; n < 4; ++n)
#pragma unroll
      for (int r = 0; r < 4; ++r)
        p_s[(rowb + 4 * g4 + r) * LDP + n * 16 + l15] = f2bf(sc[n][r]);
    f32x4 ov[2] = {zf, zf};
#pragma unroll
    for (int ks = 0; ks < 2; ++ks) {
      bf16x8 pa = *(const bf16x8*)&p_s[(rowb + l15) * LDP + ks * 32 + 8 * g4];
#pragma unroll
      for (int t2 = 0; t2 < 2; ++t2) {
        bf16x8 vb2 = *(const bf16x8*)&v_s[h][t2 * 16 + l15][ks * 32 + 8 * g4];
        ov[t2] = __builtin_amdgcn_mfma_f32_16x16x32_bf16(pa, vb2, ov[t2], 0, 0, 0);
      }
    }
#pragma unroll
    for (int t2 = 0; t2 < 2; ++t2)
#pragma unroll
      for (int r = 0; r < 4; ++r)
        h_s[rowb + 4 * g4 + r][h * 32 + t2 * 16 + l15] = f2bf(ov[t2][r] * sm[r]);
  }
  __syncthreads();

  // ---------------- Phase 4: output projection ----------------
  {
    const ushort* wsrc = ws + WS_PROJ;
    for (int m = tid; m < 1152; m += 256) {
      const int col = m / 12, kko = (m - col * 12) * 8;
      *(uint4*)&w_s[col * LDW + kko] = *(const uint4*)&wsrc[col * 96 + kko];
    }
  }
  __syncthreads();
  f32x4 po[6];
#pragma unroll
  for (int t = 0; t < 6; ++t) po[t] = zf;
#pragma unroll
  for (int ks = 0; ks < 3; ++ks) {
    bf16x8 a = *(const bf16x8*)&h_s[rowb + l15][ks * 32 + 8 * g4];
#pragma unroll
    for (int t = 0; t < 6; ++t) {
      bf16x8 bb = *(const bf16x8*)&w_s[(t * 16 + l15) * LDW + ks * 32 + 8 * g4];
      po[t] = __builtin_amdgcn_mfma_f32_16x16x32_bf16(a, bb, po[t], 0, 0, 0);
    }
  }
#pragma unroll
  for (int r = 0; r < 4; ++r) {
    const int row = rowb + 4 * g4 + r;
    const int ti2 = row >> 3, tj2 = row & 7;
    const int iy = (wy * 8 + ti2 + SHIFT) & 127;
    const int ix = (wx * 8 + tj2 + SHIFT) & 127;
    const size_t gbase = ((size_t)(b * 16384 + iy * 128 + ix)) * 96;
#pragma unroll
    for (int t = 0; t < 6; ++t) {
      const size_t gi = gbase + t * 16 + l15;
      out[gi] = x[gi] + po[t][r];
    }
  }
}

// ---------------------------------------------------------------------------
// Kernel 2: LN2 + MLP(4x, gelu-tanh) + residual, in place on d_out.
// 512 threads = 8 waves, 128 rows; alternating single weight buffer -> 73 KB
// LDS -> 2 blocks/CU.
// ---------------------------------------------------------------------------
__global__ __launch_bounds__(512, 4)
void swin_mlp_kernel(const float* __restrict__ ln2g, const float* __restrict__ ln2b,
                     const ushort* __restrict__ ws, float* xm)
{
  __shared__ ushort h_s[128][LDA];   // 26624 B
  __shared__ ushort u_s[128][LDA];   // 26624 B
  __shared__ ushort w_s[96][LDW];    // 19968 B (w1 chunk, then w2 chunk)

  const int tid = threadIdx.x, lane = tid & 63, wv = tid >> 6;
  const int l15 = lane & 15, g4 = lane >> 4;
  const size_t rowg = (size_t)blockIdx.x * 128;

  // LN2 (4 lanes per row)
  {
    const int t = tid >> 2, p = tid & 3;
    const float* rowp = xm + (rowg + t) * 96 + p * 24;
    float vb[24];
    float s = 0.f, ss = 0.f;
#pragma unroll
    for (int u = 0; u < 6; ++u) {
      f32x4 f = *(const f32x4*)(rowp + 4 * u);
#pragma unroll
      for (int e = 0; e < 4; ++e) { float q = f[e]; vb[4*u+e] = q; s += q; ss += q*q; }
    }
    s  += __shfl_xor(s, 1);  s  += __shfl_xor(s, 2);
    ss += __shfl_xor(ss, 1); ss += __shfl_xor(ss, 2);
    const float mean = s * (1.f / 96.f);
    const float var  = ss * (1.f / 96.f) - mean * mean;
    const float rstd = rsqrtf(var + 1e-5f);
#pragma unroll
    for (int u = 0; u < 6; ++u) {
      f32x4 gg = *(const f32x4*)(ln2g + p * 24 + 4 * u);
      f32x4 bb = *(const f32x4*)(ln2b + p * 24 + 4 * u);
      ushort r0 = f2bf((vb[4*u+0] - mean) * rstd * gg[0] + bb[0]);
      ushort r1 = f2bf((vb[4*u+1] - mean) * rstd * gg[1] + bb[1]);
      ushort r2 = f2bf((vb[4*u+2] - mean) * rstd * gg[2] + bb[2]);
      ushort r3 = f2bf((vb[4*u+3] - mean) * rstd * gg[3] + bb[3]);
      *(uint*)&h_s[t][p*24 + 4*u + 0] = (uint)r0 | ((uint)r1 << 16);
      *(uint*)&h_s[t][p*24 + 4*u + 2] = (uint)r2 | ((uint)r3 << 16);
    }
  }
  __syncthreads();

  const int rowb = 16 * wv;
  const f32x4 zf = {0.f, 0.f, 0.f, 0.f};
  f32x4 acc[6];
#pragma unroll
  for (int t = 0; t < 6; ++t) acc[t] = zf;

  for (int c = 0; c < 4; ++c) {   // 4 chunks of 96 hidden cols
    {  // stage w1T chunk: [96 cols][96 k]
      const ushort* wsrc = ws + WS_W1 + c * 9216;
      for (int m = tid; m < 1152; m += 512) {
        const int col = m / 12, kko = (m - col * 12) * 8;
        *(uint4*)&w_s[col][kko] = *(const uint4*)&wsrc[col * 96 + kko];
      }
    }
    __syncthreads();
    f32x4 ua[6];
#pragma unroll
    for (int t = 0; t < 6; ++t) ua[t] = zf;
#pragma unroll
    for (int ks = 0; ks < 3; ++ks) {
      bf16x8 a = *(const bf16x8*)&h_s[rowb + l15][ks * 32 + 8 * g4];
#pragma unroll
      for (int t = 0; t < 6; ++t) {
        bf16x8 bb = *(const bf16x8*)&w_s[t * 16 + l15][ks * 32 + 8 * g4];
        ua[t] = __builtin_amdgcn_mfma_f32_16x16x32_bf16(a, bb, ua[t], 0, 0, 0);
      }
    }
    // gelu (tanh approx) -> u_s (wave-local rows, no barrier needed before GEMM2)
#pragma unroll
    for (int t = 0; t < 6; ++t)
#pragma unroll
      for (int r = 0; r < 4; ++r) {
        const float v = ua[t][r];
        const float a3 = 0.7978845608028654f * (v + 0.044715f * v * v * v);
        const float e = __expf(2.f * a3);
        const float th = 1.f - 2.f / (e + 1.f);
        u_s[rowb + 4 * g4 + r][t * 16 + l15] = f2bf(0.5f * v * (1.f + th));
      }
    __syncthreads();   // all waves done reading w1 chunk
    {  // stage w2T chunk into same buffer: w_s[col][kk] = w2T[col][c*96+kk]
      const ushort* wsrc = ws + WS_W2 + c * 96;
      for (int m = tid; m < 1152; m += 512) {
        const int col = m / 12, kko = (m - col * 12) * 8;
        *(uint4*)&w_s[col][kko] = *(const uint4*)&wsrc[col * 384 + kko];
      }
    }
    __syncthreads();
#pragma unroll
    for (int ks = 0; ks < 3; ++ks) {
      bf16x8 pa = *(const bf16x8*)&u_s[rowb + l15][ks * 32 + 8 * g4];
#pragma unroll
      for (int t = 0; t < 6; ++t) {
        bf16x8 bb = *(const bf16x8*)&w_s[t * 16 + l15][ks * 32 + 8 * g4];
        acc[t] = __builtin_amdgcn_mfma_f32_16x16x32_bf16(pa, bb, acc[t], 0, 0, 0);
      }
    }
    __syncthreads();   // all waves done reading w2 chunk before next-stage overwrite
  }
  // epilogue: residual, in place (rows owned by this wave only)
#pragma unroll
  for (int r = 0; r < 4; ++r) {
    const size_t gr = (rowg + rowb + 4 * g4 + r) * 96;
#pragma unroll
    for (int t = 0; t < 6; ++t) {
      const size_t gi = gr + t * 16 + l15;
      xm[gi] = xm[gi] + acc[t][r];
    }
  }
}

extern "C" void kernel_launch(void* const* d_in, const int* in_sizes, int n_in,
                              void* d_out, int out_size, void* d_ws, size_t ws_size,
                              hipStream_t stream) {
  (void)in_sizes; (void)n_in; (void)out_size; (void)ws_size;
  const float* x     = (const float*)d_in[0];
  const float* ln1g  = (const float*)d_in[1];
  const float* ln1b  = (const float*)d_in[2];
  const float* qkvw  = (const float*)d_in[3];
  const float* qkvb  = (const float*)d_in[4];
  const float* projw = (const float*)d_in[5];
  const float* btab  = (const float*)d_in[6];
  const float* ln2g  = (const float*)d_in[7];
  const float* ln2b  = (const float*)d_in[8];
  const float* w1    = (const float*)d_in[9];
  const float* w2    = (const float*)d_in[10];
  float* out = (float*)d_out;
  ushort* ws = (ushort*)d_ws;

  swin_prep_kernel<<<432, 256, 0, stream>>>(qkvw, projw, w1, w2, ws);
  swin_attn_kernel<<<4096, 256, 0, stream>>>(x, ln1g, ln1b, ws, qkvb, btab, out);
  swin_mlp_kernel<<<2048, 512, 0, stream>>>(ln2g, ln2b, ws, out);
}

// Round 4
// 226.123 us; speedup vs baseline: 1.8387x; 1.1537x over previous
//
#include <hip/hip_runtime.h>

#define SHIFT 4

typedef __bf16 bf16x8 __attribute__((ext_vector_type(8)));
typedef __bf16 bf16x4 __attribute__((ext_vector_type(4)));
typedef float  f32x4  __attribute__((ext_vector_type(4)));

// Padded LDS leading dims.
#define LDQ 40   // q/k tiles: [3][64][LDQ]
#define LDV 72   // v transposed: [3][32][LDV]
#define LDA 104  // h / attn-out / mlp row tiles: [rows][LDA]
#define LDW 104  // transposed weight tiles: [96][LDW]  (208 B rows, 16B-aligned)
#define LDP 72   // P scratch: [64][LDP]

// ws layout:
//   bf16 weights:
//     qkvwT  [288][96] @ 0        (qkvwT[col][k] = qkvw[k][col])
//     projwT [96][96]  @ 27648
//     w1T    [384][96] @ 36864
//     w2T    [96][384] @ 73728
//   f32 bias_full [3][64][64] @ byte 221184  (window-independent rel-pos bias)
#define WS_QKV  0
#define WS_PROJ 27648
#define WS_W1   36864
#define WS_W2   73728
#define WS_TOT  110592
#define WS_BIAS_BYTES 221184

// ---------------------------------------------------------------------------
// Kernel 0: weight prep (f32 -> bf16 transposed) + full rel-pos bias tensor.
// ---------------------------------------------------------------------------
__global__ __launch_bounds__(256)
void swin_prep_kernel(const float* __restrict__ qkvw, const float* __restrict__ projw,
                      const float* __restrict__ w1, const float* __restrict__ w2,
                      const float* __restrict__ btab,
                      __bf16* __restrict__ ws)
{
  const int i = blockIdx.x * 256 + threadIdx.x;
  if (i < 27648) {                       // qkvwT
    const int col = i / 96, kk = i - col * 96;
    ws[i] = (__bf16)qkvw[kk * 288 + col];
  } else if (i < 36864) {                // projwT
    const int j = i - 27648; const int col = j / 96, kk = j - col * 96;
    ws[i] = (__bf16)projw[kk * 96 + col];
  } else if (i < 73728) {                // w1T
    const int j = i - 36864; const int col = j / 96, kk = j - col * 96;
    ws[i] = (__bf16)w1[kk * 384 + col];
  } else if (i < WS_TOT) {               // w2T
    const int j = i - 73728; const int col = j / 384, kk = j - col * 384;
    ws[i] = (__bf16)w2[kk * 96 + col];
  } else {                               // bias_full[h][n][m], grid sized exactly
    const int j = i - WS_TOT;            // j < 12288
    const int h = j >> 12, n = (j >> 6) & 63, m = j & 63;
    const int dy = (n >> 3) - (m >> 3), dx = (n & 7) - (m & 7);
    const int idx = (dy + 7) * 15 + (dx + 7);
    float* biasf = (float*)((char*)ws + WS_BIAS_BYTES);
    biasf[j] = btab[idx * 3 + h];
  }
}

// ---------------------------------------------------------------------------
// Kernel 1: LN1 + shift + window partition + windowed MHSA + proj + residual.
// One block = one 8x8 window (64 tokens). 256 threads = 4 waves.
// ---------------------------------------------------------------------------
__global__ __launch_bounds__(256, 2)
void swin_attn_kernel(const float* __restrict__ x,
                      const float* __restrict__ ln1g, const float* __restrict__ ln1b,
                      const __bf16* __restrict__ ws, const float* __restrict__ qkvb,
                      float* __restrict__ out)
{
  __shared__ __bf16 q_s[3][64][LDQ];             // 15360 B
  __shared__ __bf16 k_s[3][64][LDQ];             // 15360 B
  __shared__ __bf16 v_s[3][32][LDV];             // 13824 B
  __shared__ __bf16 h_s[64][LDA];                // 13312 B
  __shared__ __align__(16) char uni[96 * LDW * 2]; // 19968 B union:
  __bf16* w_s = (__bf16*)uni;                    //   weight chunk [96][LDW]
  __bf16* p_s = (__bf16*)uni;                    //   P scratch [64][LDP]

  const float* biasf = (const float*)((const char*)ws + WS_BIAS_BYTES);

  const int tid  = threadIdx.x;
  const int lane = tid & 63;
  const int wv   = tid >> 6;
  const int l15  = lane & 15;
  const int g4   = lane >> 4;
  const int blk  = blockIdx.x;          // b*256 + wy*16 + wx
  const int b    = blk >> 8;
  const int wy   = (blk >> 4) & 15;
  const int wx   = blk & 15;

  // ---------------- Phase 1: LayerNorm (4 lanes per token) ----------------
  {
    const int t = tid >> 2, p = tid & 3;
    const int ti = t >> 3, tj = t & 7;
    const int iy = (wy * 8 + ti + SHIFT) & 127;
    const int ix = (wx * 8 + tj + SHIFT) & 127;
    const float* rowp = x + ((size_t)(b * 16384 + iy * 128 + ix)) * 96 + p * 24;
    float vb[24];
    float s = 0.f, ss = 0.f;
#pragma unroll
    for (int u = 0; u < 6; ++u) {
      f32x4 f = *(const f32x4*)(rowp + 4 * u);
#pragma unroll
      for (int e = 0; e < 4; ++e) { float q = f[e]; vb[4*u+e] = q; s += q; ss += q*q; }
    }
    s  += __shfl_xor(s, 1);  s  += __shfl_xor(s, 2);
    ss += __shfl_xor(ss, 1); ss += __shfl_xor(ss, 2);
    const float mean = s * (1.f / 96.f);
    const float var  = ss * (1.f / 96.f) - mean * mean;
    const float rstd = rsqrtf(var + 1e-5f);
#pragma unroll
    for (int u = 0; u < 6; ++u) {
      f32x4 gg = *(const f32x4*)(ln1g + p * 24 + 4 * u);
      f32x4 bb = *(const f32x4*)(ln1b + p * 24 + 4 * u);
      f32x4 nv;
#pragma unroll
      for (int e = 0; e < 4; ++e) nv[e] = (vb[4*u+e] - mean) * rstd * gg[e] + bb[e];
      *(bf16x4*)&h_s[t][p * 24 + 4 * u] = __builtin_convertvector(nv, bf16x4);
    }
  }
  __syncthreads();

  // ---------------- Phase 2: QKV projection (3 chunks of 96 cols) ----------
  const float qscale = 0.17677669529663687f;  // 1/sqrt(32)
  for (int c = 0; c < 3; ++c) {
    const __bf16* wsrc = ws + WS_QKV + c * 9216;        // [96 cols][96 k]
    for (int m = tid; m < 1152; m += 256) {             // 16B-chunk copy
      const int col = m / 12, kko = (m - col * 12) * 8;
      *(uint4*)&w_s[col * LDW + kko] = *(const uint4*)&wsrc[col * 96 + kko];
    }
    __syncthreads();
    f32x4 acc[6];
#pragma unroll
    for (int t = 0; t < 6; ++t) {
      const float bv = qkvb[c * 96 + t * 16 + l15];
      f32x4 a4 = {bv, bv, bv, bv};
      acc[t] = a4;
    }
#pragma unroll
    for (int ks = 0; ks < 3; ++ks) {
      bf16x8 a = *(const bf16x8*)&h_s[16 * wv + l15][ks * 32 + 8 * g4];
#pragma unroll
      for (int t = 0; t < 6; ++t) {
        bf16x8 bb = *(const bf16x8*)&w_s[(t * 16 + l15) * LDW + ks * 32 + 8 * g4];
        acc[t] = __builtin_amdgcn_mfma_f32_16x16x32_bf16(a, bb, acc[t], 0, 0, 0);
      }
    }
    // scatter: D col = l15(+16t), row = 16wv + 4*g4 + reg
    if (c < 2) {
#pragma unroll
      for (int t = 0; t < 6; ++t) {
        const int head = t >> 1, dim = (t & 1) * 16 + l15;
#pragma unroll
        for (int r = 0; r < 4; ++r) {
          const int tok = 16 * wv + 4 * g4 + r;
          if (c == 0) q_s[head][tok][dim] = (__bf16)(acc[t][r] * qscale);
          else        k_s[head][tok][dim] = (__bf16)acc[t][r];
        }
      }
    } else {  // v transposed [head][dim][tok]; 4 regs = 4 consecutive toks
#pragma unroll
      for (int t = 0; t < 6; ++t) {
        const int head = t >> 1, dim = (t & 1) * 16 + l15;
        *(bf16x4*)&v_s[head][dim][16 * wv + 4 * g4] =
            __builtin_convertvector(acc[t], bf16x4);
      }
    }
    __syncthreads();
  }

  // ---------------- Phase 3: attention, head by head ----------------
  const int rowb = 16 * wv;
  int qry[4], qrx[4];
#pragma unroll
  for (int r = 0; r < 4; ++r) {
    const int row = rowb + 4 * g4 + r;
    const int ti2 = row >> 3, tj2 = row & 7;
    qry[r] = (wy == 15) ? (ti2 < 4 ? 1 : 2) : 0;
    qrx[r] = (wx == 15) ? (tj2 < 4 ? 1 : 2) : 0;
  }
  const f32x4 zf = {0.f, 0.f, 0.f, 0.f};
  for (int h = 0; h < 3; ++h) {
    // issue bias loads early (L2-hot, contiguous per 16 lanes)
    const float* bh = biasf + h * 4096;
    float bv[4][4];
#pragma unroll
    for (int n = 0; n < 4; ++n)
#pragma unroll
      for (int r = 0; r < 4; ++r)
        bv[n][r] = bh[(rowb + 4 * g4 + r) * 64 + n * 16 + l15];

    bf16x8 aq = *(const bf16x8*)&q_s[h][rowb + l15][8 * g4];
    f32x4 sc[4];
#pragma unroll
    for (int n = 0; n < 4; ++n) {
      bf16x8 bk = *(const bf16x8*)&k_s[h][n * 16 + l15][8 * g4];
      sc[n] = __builtin_amdgcn_mfma_f32_16x16x32_bf16(aq, bk, zf, 0, 0, 0);
    }
#pragma unroll
    for (int n = 0; n < 4; ++n) {
      const int colt = n * 16 + l15;
      const int ki = colt >> 3, kj = colt & 7;
      const int kry = (wy == 15) ? (ki < 4 ? 1 : 2) : 0;
      const int krx = (wx == 15) ? (kj < 4 ? 1 : 2) : 0;
#pragma unroll
      for (int r = 0; r < 4; ++r) {
        const float mk = (qry[r] == kry && qrx[r] == krx) ? 0.f : -100.f;
        sc[n][r] += bv[n][r] + mk;
      }
    }
    float mx[4], sm[4];
#pragma unroll
    for (int r = 0; r < 4; ++r) {
      float m = fmaxf(fmaxf(sc[0][r], sc[1][r]), fmaxf(sc[2][r], sc[3][r]));
      m = fmaxf(m, __shfl_xor(m, 1)); m = fmaxf(m, __shfl_xor(m, 2));
      m = fmaxf(m, __shfl_xor(m, 4)); m = fmaxf(m, __shfl_xor(m, 8));
      mx[r] = m; sm[r] = 0.f;
    }
#pragma unroll
    for (int n = 0; n < 4; ++n)
#pragma unroll
      for (int r = 0; r < 4; ++r) {
        float p = __expf(sc[n][r] - mx[r]); sc[n][r] = p; sm[r] += p;
      }
#pragma unroll
    for (int r = 0; r < 4; ++r) {
      float s2 = sm[r];
      s2 += __shfl_xor(s2, 1); s2 += __shfl_xor(s2, 2);
      s2 += __shfl_xor(s2, 4); s2 += __shfl_xor(s2, 8);
      sm[r] = __builtin_amdgcn_rcpf(s2);
    }
#pragma unroll
    for (int n = 0; n < 4; ++n)
#pragma unroll
      for (int r = 0; r < 4; ++r)
        p_s[(rowb + 4 * g4 + r) * LDP + n * 16 + l15] = (__bf16)sc[n][r];
    f32x4 ov[2] = {zf, zf};
#pragma unroll
    for (int ks = 0; ks < 2; ++ks) {
      bf16x8 pa = *(const bf16x8*)&p_s[(rowb + l15) * LDP + ks * 32 + 8 * g4];
#pragma unroll
      for (int t2 = 0; t2 < 2; ++t2) {
        bf16x8 vb2 = *(const bf16x8*)&v_s[h][t2 * 16 + l15][ks * 32 + 8 * g4];
        ov[t2] = __builtin_amdgcn_mfma_f32_16x16x32_bf16(pa, vb2, ov[t2], 0, 0, 0);
      }
    }
#pragma unroll
    for (int t2 = 0; t2 < 2; ++t2)
#pragma unroll
      for (int r = 0; r < 4; ++r)
        h_s[rowb + 4 * g4 + r][h * 32 + t2 * 16 + l15] = (__bf16)(ov[t2][r] * sm[r]);
  }
  __syncthreads();

  // ---------------- Phase 4: output projection ----------------
  {
    const __bf16* wsrc = ws + WS_PROJ;
    for (int m = tid; m < 1152; m += 256) {
      const int col = m / 12, kko = (m - col * 12) * 8;
      *(uint4*)&w_s[col * LDW + kko] = *(const uint4*)&wsrc[col * 96 + kko];
    }
  }
  __syncthreads();
  f32x4 po[6];
#pragma unroll
  for (int t = 0; t < 6; ++t) po[t] = zf;
#pragma unroll
  for (int ks = 0; ks < 3; ++ks) {
    bf16x8 a = *(const bf16x8*)&h_s[rowb + l15][ks * 32 + 8 * g4];
#pragma unroll
    for (int t = 0; t < 6; ++t) {
      bf16x8 bb = *(const bf16x8*)&w_s[(t * 16 + l15) * LDW + ks * 32 + 8 * g4];
      po[t] = __builtin_amdgcn_mfma_f32_16x16x32_bf16(a, bb, po[t], 0, 0, 0);
    }
  }
#pragma unroll
  for (int r = 0; r < 4; ++r) {
    const int row = rowb + 4 * g4 + r;
    const int ti2 = row >> 3, tj2 = row & 7;
    const int iy = (wy * 8 + ti2 + SHIFT) & 127;
    const int ix = (wx * 8 + tj2 + SHIFT) & 127;
    const size_t gbase = ((size_t)(b * 16384 + iy * 128 + ix)) * 96;
#pragma unroll
    for (int t = 0; t < 6; ++t) {
      const size_t gi = gbase + t * 16 + l15;
      out[gi] = x[gi] + po[t][r];
    }
  }
}

// ---------------------------------------------------------------------------
// Kernel 2: LN2 + MLP(4x, gelu-tanh) + residual, in place on d_out.
// 512 threads = 8 waves, 128 rows; alternating single weight buffer.
// ---------------------------------------------------------------------------
__global__ __launch_bounds__(512, 4)
void swin_mlp_kernel(const float* __restrict__ ln2g, const float* __restrict__ ln2b,
                     const __bf16* __restrict__ ws, float* xm)
{
  __shared__ __bf16 h_s[128][LDA];   // 26624 B
  __shared__ __bf16 u_s[128][LDA];   // 26624 B
  __shared__ __bf16 w_s[96][LDW];    // 19968 B (w1 chunk, then w2 chunk)

  const int tid = threadIdx.x, lane = tid & 63, wv = tid >> 6;
  const int l15 = lane & 15, g4 = lane >> 4;
  const size_t rowg = (size_t)blockIdx.x * 128;

  // LN2 (4 lanes per row)
  {
    const int t = tid >> 2, p = tid & 3;
    const float* rowp = xm + (rowg + t) * 96 + p * 24;
    float vb[24];
    float s = 0.f, ss = 0.f;
#pragma unroll
    for (int u = 0; u < 6; ++u) {
      f32x4 f = *(const f32x4*)(rowp + 4 * u);
#pragma unroll
      for (int e = 0; e < 4; ++e) { float q = f[e]; vb[4*u+e] = q; s += q; ss += q*q; }
    }
    s  += __shfl_xor(s, 1);  s  += __shfl_xor(s, 2);
    ss += __shfl_xor(ss, 1); ss += __shfl_xor(ss, 2);
    const float mean = s * (1.f / 96.f);
    const float var  = ss * (1.f / 96.f) - mean * mean;
    const float rstd = rsqrtf(var + 1e-5f);
#pragma unroll
    for (int u = 0; u < 6; ++u) {
      f32x4 gg = *(const f32x4*)(ln2g + p * 24 + 4 * u);
      f32x4 bb = *(const f32x4*)(ln2b + p * 24 + 4 * u);
      f32x4 nv;
#pragma unroll
      for (int e = 0; e < 4; ++e) nv[e] = (vb[4*u+e] - mean) * rstd * gg[e] + bb[e];
      *(bf16x4*)&h_s[t][p * 24 + 4 * u] = __builtin_convertvector(nv, bf16x4);
    }
  }
  __syncthreads();

  const int rowb = 16 * wv;
  const f32x4 zf = {0.f, 0.f, 0.f, 0.f};
  f32x4 acc[6];
#pragma unroll
  for (int t = 0; t < 6; ++t) acc[t] = zf;

  for (int c = 0; c < 4; ++c) {   // 4 chunks of 96 hidden cols
    {  // stage w1T chunk: [96 cols][96 k]
      const __bf16* wsrc = ws + WS_W1 + c * 9216;
      for (int m = tid; m < 1152; m += 512) {
        const int col = m / 12, kko = (m - col * 12) * 8;
        *(uint4*)&w_s[col][kko] = *(const uint4*)&wsrc[col * 96 + kko];
      }
    }
    __syncthreads();
    f32x4 ua[6];
#pragma unroll
    for (int t = 0; t < 6; ++t) ua[t] = zf;
#pragma unroll
    for (int ks = 0; ks < 3; ++ks) {
      bf16x8 a = *(const bf16x8*)&h_s[rowb + l15][ks * 32 + 8 * g4];
#pragma unroll
      for (int t = 0; t < 6; ++t) {
        bf16x8 bb = *(const bf16x8*)&w_s[t * 16 + l15][ks * 32 + 8 * g4];
        ua[t] = __builtin_amdgcn_mfma_f32_16x16x32_bf16(a, bb, ua[t], 0, 0, 0);
      }
    }
    // gelu (tanh approx): v*e/(e+1) with e=exp(2*a3); rcp instead of divide
#pragma unroll
    for (int t = 0; t < 6; ++t)
#pragma unroll
      for (int r = 0; r < 4; ++r) {
        const float v = ua[t][r];
        const float a3 = 0.7978845608028654f * (v + 0.044715f * v * v * v);
        const float e = __expf(2.f * a3);
        const float g = v - v * __builtin_amdgcn_rcpf(e + 1.f);
        u_s[rowb + 4 * g4 + r][t * 16 + l15] = (__bf16)g;
      }
    __syncthreads();   // all waves done reading w1 chunk
    {  // stage w2T chunk into same buffer
      const __bf16* wsrc = ws + WS_W2 + c * 96;
      for (int m = tid; m < 1152; m += 512) {
        const int col = m / 12, kko = (m - col * 12) * 8;
        *(uint4*)&w_s[col][kko] = *(const uint4*)&wsrc[col * 384 + kko];
      }
    }
    __syncthreads();
#pragma unroll
    for (int ks = 0; ks < 3; ++ks) {
      bf16x8 pa = *(const bf16x8*)&u_s[rowb + l15][ks * 32 + 8 * g4];
#pragma unroll
      for (int t = 0; t < 6; ++t) {
        bf16x8 bb = *(const bf16x8*)&w_s[t * 16 + l15][ks * 32 + 8 * g4];
        acc[t] = __builtin_amdgcn_mfma_f32_16x16x32_bf16(pa, bb, acc[t], 0, 0, 0);
      }
    }
    __syncthreads();   // all waves done reading w2 chunk before next overwrite
  }
  // epilogue: residual, in place (rows owned by this wave only)
#pragma unroll
  for (int r = 0; r < 4; ++r) {
    const size_t gr = (rowg + rowb + 4 * g4 + r) * 96;
#pragma unroll
    for (int t = 0; t < 6; ++t) {
      const size_t gi = gr + t * 16 + l15;
      xm[gi] = xm[gi] + acc[t][r];
    }
  }
}

extern "C" void kernel_launch(void* const* d_in, const int* in_sizes, int n_in,
                              void* d_out, int out_size, void* d_ws, size_t ws_size,
                              hipStream_t stream) {
  (void)in_sizes; (void)n_in; (void)out_size; (void)ws_size;
  const float* x     = (const float*)d_in[0];
  const float* ln1g  = (const float*)d_in[1];
  const float* ln1b  = (const float*)d_in[2];
  const float* qkvw  = (const float*)d_in[3];
  const float* qkvb  = (const float*)d_in[4];
  const float* projw = (const float*)d_in[5];
  const float* btab  = (const float*)d_in[6];
  const float* ln2g  = (const float*)d_in[7];
  const float* ln2b  = (const float*)d_in[8];
  const float* w1    = (const float*)d_in[9];
  const float* w2    = (const float*)d_in[10];
  float* out = (float*)d_out;
  __bf16* ws = (__bf16*)d_ws;

  // 122880 items = 110592 weight elems + 12288 bias elems (grid covers exactly)
  swin_prep_kernel<<<480, 256, 0, stream>>>(qkvw, projw, w1, w2, btab, ws);
  swin_attn_kernel<<<4096, 256, 0, stream>>>(x, ln1g, ln1b, ws, qkvb, out);
  swin_mlp_kernel<<<2048, 512, 0, stream>>>(ln2g, ln2b, ws, out);
}

// Round 5
// 198.722 us; speedup vs baseline: 2.0922x; 1.1379x over previous
//
#include <hip/hip_runtime.h>

#define SHIFT 4

typedef __bf16 bf16x8 __attribute__((ext_vector_type(8)));
typedef __bf16 bf16x4 __attribute__((ext_vector_type(4)));
typedef float  f32x4  __attribute__((ext_vector_type(4)));

// Padded LDS leading dims.
#define LDQ 40   // q/k tiles: [3][64][LDQ]
#define LDV 72   // v transposed: [3][32][LDV]
#define LDA 104  // h / mlp row tiles: [rows][LDA]
#define LDP 72   // P scratch: [64][LDP]

// ws layout, FRAGMENT-ORDERED bf16 weights:
//   frag f = 512 bf16 = 1KB: lane L holds the 8 contiguous contraction-dim
//   values for MFMA B-operand (col = t*16 + (L&15), k = ks*32 + (L>>4)*8 ..+7).
//   frag id: qkv   c*18 + t*3 + ks      (f 0..53)
//            proj  54 + t*3 + ks        (f 54..71)
//            w1    72 + c*18 + t*3+ks   (f 72..143)
//            w2    144 + c*18 + t*3+ks  (f 144..215)
//   f32 bias_full [3][64][64] @ byte 221184
#define WS_BIAS_BYTES 221184

// ---------------------------------------------------------------------------
// Kernel 0: weight prep -> bf16 fragment-ordered; full rel-pos bias tensor.
// ---------------------------------------------------------------------------
__global__ __launch_bounds__(256)
void swin_prep_kernel(const float* __restrict__ qkvw, const float* __restrict__ projw,
                      const float* __restrict__ w1, const float* __restrict__ w2,
                      const float* __restrict__ btab,
                      __bf16* __restrict__ ws)
{
  const int i = blockIdx.x * 256 + threadIdx.x;
  if (i < 110592) {
    const int fi = i >> 9;               // fragment id 0..215
    const int e  = i & 511;
    const int lane = e >> 3, j = e & 7;
    const int l15 = lane & 15;
    const int kk  = (lane >> 4) * 8 + j; // k-offset within 32-wide ks slice
    float v;
    if (fi < 54) {                       // qkvw [96][288]
      const int c = fi / 18, rem = fi % 18, t = rem / 3, ks = rem % 3;
      v = qkvw[(ks * 32 + kk) * 288 + c * 96 + t * 16 + l15];
    } else if (fi < 72) {                // projw [96][96]
      const int f2 = fi - 54, t = f2 / 3, ks = f2 % 3;
      v = projw[(ks * 32 + kk) * 96 + t * 16 + l15];
    } else if (fi < 144) {               // w1 [96][384]
      const int f2 = fi - 72, c = f2 / 18, rem = f2 % 18, t = rem / 3, ks = rem % 3;
      v = w1[(ks * 32 + kk) * 384 + c * 96 + t * 16 + l15];
    } else {                             // w2 [384][96]
      const int f2 = fi - 144, c = f2 / 18, rem = f2 % 18, t = rem / 3, ks = rem % 3;
      v = w2[(c * 96 + ks * 32 + kk) * 96 + t * 16 + l15];
    }
    ws[i] = (__bf16)v;
  } else {                               // bias_full[h][n][m]
    const int jj = i - 110592;           // < 12288
    const int h = jj >> 12, n = (jj >> 6) & 63, m = jj & 63;
    const int dy = (n >> 3) - (m >> 3), dx = (n & 7) - (m & 7);
    float* biasf = (float*)((char*)ws + WS_BIAS_BYTES);
    biasf[jj] = btab[((dy + 7) * 15 + (dx + 7)) * 3 + h];
  }
}

// ---------------------------------------------------------------------------
// Kernel 1: LN1 + shift + window partition + windowed MHSA + proj + residual.
// One block = one 8x8 window. 256 threads = 4 waves; wave wv owns rows
// 16wv..16wv+15 of every per-window matrix end-to-end => LDS is wave-local
// everywhere except k_s/v_s, so ONE barrier total.
// ---------------------------------------------------------------------------
__global__ __launch_bounds__(256, 2)
void swin_attn_kernel(const float* __restrict__ x,
                      const float* __restrict__ ln1g, const float* __restrict__ ln1b,
                      const __bf16* __restrict__ ws, const float* __restrict__ qkvb,
                      float* __restrict__ out)
{
  __shared__ __bf16 q_s[3][64][LDQ];   // 15360 B
  __shared__ __bf16 k_s[3][64][LDQ];   // 15360 B
  __shared__ __bf16 v_s[3][32][LDV];   // 13824 B
  __shared__ __bf16 h_s[64][LDA];      // 13312 B
  __shared__ __bf16 p_s[64][LDP];      //  9216 B   => 67072 B total, 2 blocks/CU

  const float* biasf = (const float*)((const char*)ws + WS_BIAS_BYTES);

  const int tid  = threadIdx.x;
  const int lane = tid & 63;
  const int wv   = tid >> 6;
  const int l15  = lane & 15;
  const int g4   = lane >> 4;
  const int blk  = blockIdx.x;          // b*256 + wy*16 + wx
  const int b    = blk >> 8;
  const int wy   = (blk >> 4) & 15;
  const int wx   = blk & 15;

  // ---------------- Phase 1: LayerNorm (4 lanes per token; wave-local rows) --
  {
    const int t = tid >> 2, p = tid & 3;
    const int ti = t >> 3, tj = t & 7;
    const int iy = (wy * 8 + ti + SHIFT) & 127;
    const int ix = (wx * 8 + tj + SHIFT) & 127;
    const float* rowp = x + ((size_t)(b * 16384 + iy * 128 + ix)) * 96 + p * 24;
    float vb[24];
    float s = 0.f, ss = 0.f;
#pragma unroll
    for (int u = 0; u < 6; ++u) {
      f32x4 f = *(const f32x4*)(rowp + 4 * u);
#pragma unroll
      for (int e = 0; e < 4; ++e) { float q = f[e]; vb[4*u+e] = q; s += q; ss += q*q; }
    }
    s  += __shfl_xor(s, 1);  s  += __shfl_xor(s, 2);
    ss += __shfl_xor(ss, 1); ss += __shfl_xor(ss, 2);
    const float mean = s * (1.f / 96.f);
    const float var  = ss * (1.f / 96.f) - mean * mean;
    const float rstd = rsqrtf(var + 1e-5f);
#pragma unroll
    for (int u = 0; u < 6; ++u) {
      f32x4 gg = *(const f32x4*)(ln1g + p * 24 + 4 * u);
      f32x4 bb = *(const f32x4*)(ln1b + p * 24 + 4 * u);
      f32x4 nv;
#pragma unroll
      for (int e = 0; e < 4; ++e) nv[e] = (vb[4*u+e] - mean) * rstd * gg[e] + bb[e];
      *(bf16x4*)&h_s[t][p * 24 + 4 * u] = __builtin_convertvector(nv, bf16x4);
    }
  }
  // no barrier: each wave reads only its own h_s rows below

  // ---------------- Phase 2: QKV projection, B-frags direct from global -----
  const float qscale = 0.17677669529663687f;  // 1/sqrt(32)
  const __bf16* fbase = ws + (size_t)lane * 8;
  for (int c = 0; c < 3; ++c) {
    bf16x8 wf[6][3];
#pragma unroll
    for (int t = 0; t < 6; ++t)
#pragma unroll
      for (int ks = 0; ks < 3; ++ks)
        wf[t][ks] = *(const bf16x8*)(fbase + (size_t)(c * 18 + t * 3 + ks) * 512);
    f32x4 acc[6];
#pragma unroll
    for (int t = 0; t < 6; ++t) {
      const float bv = qkvb[c * 96 + t * 16 + l15];
      f32x4 a4 = {bv, bv, bv, bv};
      acc[t] = a4;
    }
#pragma unroll
    for (int ks = 0; ks < 3; ++ks) {
      bf16x8 a = *(const bf16x8*)&h_s[16 * wv + l15][ks * 32 + 8 * g4];
#pragma unroll
      for (int t = 0; t < 6; ++t)
        acc[t] = __builtin_amdgcn_mfma_f32_16x16x32_bf16(a, wf[t][ks], acc[t], 0, 0, 0);
    }
    // scatter (wave-local rows): D col=l15(+16t), row = 16wv + 4*g4 + reg
    if (c < 2) {
#pragma unroll
      for (int t = 0; t < 6; ++t) {
        const int head = t >> 1, dim = (t & 1) * 16 + l15;
#pragma unroll
        for (int r = 0; r < 4; ++r) {
          const int tok = 16 * wv + 4 * g4 + r;
          if (c == 0) q_s[head][tok][dim] = (__bf16)(acc[t][r] * qscale);
          else        k_s[head][tok][dim] = (__bf16)acc[t][r];
        }
      }
    } else {  // v transposed [head][dim][tok]; 4 regs = 4 consecutive toks
#pragma unroll
      for (int t = 0; t < 6; ++t) {
        const int head = t >> 1, dim = (t & 1) * 16 + l15;
        *(bf16x4*)&v_s[head][dim][16 * wv + 4 * g4] =
            __builtin_convertvector(acc[t], bf16x4);
      }
    }
  }

  __syncthreads();   // the ONLY barrier: k_s/v_s become visible to all waves

  // ---------------- Phase 3: attention, head by head ----------------
  const int rowb = 16 * wv;
  int qry[4], qrx[4];
#pragma unroll
  for (int r = 0; r < 4; ++r) {
    const int row = rowb + 4 * g4 + r;
    const int ti2 = row >> 3, tj2 = row & 7;
    qry[r] = (wy == 15) ? (ti2 < 4 ? 1 : 2) : 0;
    qrx[r] = (wx == 15) ? (tj2 < 4 ? 1 : 2) : 0;
  }
  const f32x4 zf = {0.f, 0.f, 0.f, 0.f};
  for (int h = 0; h < 3; ++h) {
    // bias loads issued early (L2-hot, contiguous per 16 lanes)
    const float* bh = biasf + h * 4096;
    float bv[4][4];
#pragma unroll
    for (int n = 0; n < 4; ++n)
#pragma unroll
      for (int r = 0; r < 4; ++r)
        bv[n][r] = bh[(rowb + 4 * g4 + r) * 64 + n * 16 + l15];

    bf16x8 aq = *(const bf16x8*)&q_s[h][rowb + l15][8 * g4];
    f32x4 sc[4];
#pragma unroll
    for (int n = 0; n < 4; ++n) {
      bf16x8 bk = *(const bf16x8*)&k_s[h][n * 16 + l15][8 * g4];
      sc[n] = __builtin_amdgcn_mfma_f32_16x16x32_bf16(aq, bk, zf, 0, 0, 0);
    }
#pragma unroll
    for (int n = 0; n < 4; ++n) {
      const int colt = n * 16 + l15;
      const int ki = colt >> 3, kj = colt & 7;
      const int kry = (wy == 15) ? (ki < 4 ? 1 : 2) : 0;
      const int krx = (wx == 15) ? (kj < 4 ? 1 : 2) : 0;
#pragma unroll
      for (int r = 0; r < 4; ++r) {
        const float mk = (qry[r] == kry && qrx[r] == krx) ? 0.f : -100.f;
        sc[n][r] += bv[n][r] + mk;
      }
    }
    float mx[4], sm[4];
#pragma unroll
    for (int r = 0; r < 4; ++r) {
      float m = fmaxf(fmaxf(sc[0][r], sc[1][r]), fmaxf(sc[2][r], sc[3][r]));
      m = fmaxf(m, __shfl_xor(m, 1)); m = fmaxf(m, __shfl_xor(m, 2));
      m = fmaxf(m, __shfl_xor(m, 4)); m = fmaxf(m, __shfl_xor(m, 8));
      mx[r] = m; sm[r] = 0.f;
    }
#pragma unroll
    for (int n = 0; n < 4; ++n)
#pragma unroll
      for (int r = 0; r < 4; ++r) {
        float p = __expf(sc[n][r] - mx[r]); sc[n][r] = p; sm[r] += p;
      }
#pragma unroll
    for (int r = 0; r < 4; ++r) {
      float s2 = sm[r];
      s2 += __shfl_xor(s2, 1); s2 += __shfl_xor(s2, 2);
      s2 += __shfl_xor(s2, 4); s2 += __shfl_xor(s2, 8);
      sm[r] = __builtin_amdgcn_rcpf(s2);
    }
#pragma unroll
    for (int n = 0; n < 4; ++n)
#pragma unroll
      for (int r = 0; r < 4; ++r)
        p_s[rowb + 4 * g4 + r][n * 16 + l15] = (__bf16)sc[n][r];
    f32x4 ov[2] = {zf, zf};
#pragma unroll
    for (int ks = 0; ks < 2; ++ks) {
      bf16x8 pa = *(const bf16x8*)&p_s[rowb + l15][ks * 32 + 8 * g4];
#pragma unroll
      for (int t2 = 0; t2 < 2; ++t2) {
        bf16x8 vb2 = *(const bf16x8*)&v_s[h][t2 * 16 + l15][ks * 32 + 8 * g4];
        ov[t2] = __builtin_amdgcn_mfma_f32_16x16x32_bf16(pa, vb2, ov[t2], 0, 0, 0);
      }
    }
#pragma unroll
    for (int t2 = 0; t2 < 2; ++t2)
#pragma unroll
      for (int r = 0; r < 4; ++r)
        h_s[rowb + 4 * g4 + r][h * 32 + t2 * 16 + l15] = (__bf16)(ov[t2][r] * sm[r]);
  }
  // no barrier: proj reads only this wave's h_s rows

  // ---------------- Phase 4: output projection (B-frags direct) -------------
  f32x4 po[6];
#pragma unroll
  for (int t = 0; t < 6; ++t) po[t] = zf;
#pragma unroll
  for (int ks = 0; ks < 3; ++ks) {
    bf16x8 a = *(const bf16x8*)&h_s[rowb + l15][ks * 32 + 8 * g4];
#pragma unroll
    for (int t = 0; t < 6; ++t) {
      bf16x8 bb = *(const bf16x8*)(fbase + (size_t)(54 + t * 3 + ks) * 512);
      po[t] = __builtin_amdgcn_mfma_f32_16x16x32_bf16(a, bb, po[t], 0, 0, 0);
    }
  }
  // epilogue: window reverse + unshift + residual (x re-read, LLC-hot)
#pragma unroll
  for (int r = 0; r < 4; ++r) {
    const int row = rowb + 4 * g4 + r;
    const int ti2 = row >> 3, tj2 = row & 7;
    const int iy = (wy * 8 + ti2 + SHIFT) & 127;
    const int ix = (wx * 8 + tj2 + SHIFT) & 127;
    const size_t gbase = ((size_t)(b * 16384 + iy * 128 + ix)) * 96;
#pragma unroll
    for (int t = 0; t < 6; ++t) {
      const size_t gi = gbase + t * 16 + l15;
      out[gi] = x[gi] + po[t][r];
    }
  }
}

// ---------------------------------------------------------------------------
// Kernel 2: LN2 + MLP(4x, gelu-tanh) + residual, in place on d_out.
// 256 threads = 4 waves, 64 rows; everything wave-local => ZERO barriers.
// B-fragments direct from global (fragment-ordered, L1/L2-hot).
// ---------------------------------------------------------------------------
__global__ __launch_bounds__(256, 4)
void swin_mlp_kernel(const float* __restrict__ ln2g, const float* __restrict__ ln2b,
                     const __bf16* __restrict__ ws, float* xm)
{
  __shared__ __bf16 h_s[64][LDA];   // 13312 B
  __shared__ __bf16 u_s[64][LDA];   // 13312 B  => 26624 B total

  const int tid = threadIdx.x, lane = tid & 63, wv = tid >> 6;
  const int l15 = lane & 15, g4 = lane >> 4;
  const size_t rowg = (size_t)blockIdx.x * 64;

  // LN2 (4 lanes per row; wave-local rows)
  {
    const int t = tid >> 2, p = tid & 3;
    const float* rowp = xm + (rowg + t) * 96 + p * 24;
    float vb[24];
    float s = 0.f, ss = 0.f;
#pragma unroll
    for (int u = 0; u < 6; ++u) {
      f32x4 f = *(const f32x4*)(rowp + 4 * u);
#pragma unroll
      for (int e = 0; e < 4; ++e) { float q = f[e]; vb[4*u+e] = q; s += q; ss += q*q; }
    }
    s  += __shfl_xor(s, 1);  s  += __shfl_xor(s, 2);
    ss += __shfl_xor(ss, 1); ss += __shfl_xor(ss, 2);
    const float mean = s * (1.f / 96.f);
    const float var  = ss * (1.f / 96.f) - mean * mean;
    const float rstd = rsqrtf(var + 1e-5f);
#pragma unroll
    for (int u = 0; u < 6; ++u) {
      f32x4 gg = *(const f32x4*)(ln2g + p * 24 + 4 * u);
      f32x4 bb = *(const f32x4*)(ln2b + p * 24 + 4 * u);
      f32x4 nv;
#pragma unroll
      for (int e = 0; e < 4; ++e) nv[e] = (vb[4*u+e] - mean) * rstd * gg[e] + bb[e];
      *(bf16x4*)&h_s[t][p * 24 + 4 * u] = __builtin_convertvector(nv, bf16x4);
    }
  }
  // no barrier

  const int rowb = 16 * wv;
  const f32x4 zf = {0.f, 0.f, 0.f, 0.f};
  const __bf16* fbase = ws + (size_t)lane * 8;
  f32x4 acc[6];
#pragma unroll
  for (int t = 0; t < 6; ++t) acc[t] = zf;

  for (int c = 0; c < 4; ++c) {   // 4 chunks of 96 hidden cols
    f32x4 ua[6];
#pragma unroll
    for (int t = 0; t < 6; ++t) ua[t] = zf;
#pragma unroll
    for (int ks = 0; ks < 3; ++ks) {
      bf16x8 a = *(const bf16x8*)&h_s[rowb + l15][ks * 32 + 8 * g4];
      const __bf16* f1 = fbase + (size_t)(72 + c * 18 + ks) * 512;
#pragma unroll
      for (int t = 0; t < 6; ++t) {
        bf16x8 bb = *(const bf16x8*)(f1 + (size_t)t * 3 * 512);
        ua[t] = __builtin_amdgcn_mfma_f32_16x16x32_bf16(a, bb, ua[t], 0, 0, 0);
      }
    }
    // gelu (tanh approx) -> u_s (wave-local rows)
#pragma unroll
    for (int t = 0; t < 6; ++t)
#pragma unroll
      for (int r = 0; r < 4; ++r) {
        const float v = ua[t][r];
        const float a3 = 0.7978845608028654f * (v + 0.044715f * v * v * v);
        const float e = __expf(2.f * a3);
        const float g = v - v * __builtin_amdgcn_rcpf(e + 1.f);
        u_s[rowb + 4 * g4 + r][t * 16 + l15] = (__bf16)g;
      }
#pragma unroll
    for (int ks = 0; ks < 3; ++ks) {
      bf16x8 pa = *(const bf16x8*)&u_s[rowb + l15][ks * 32 + 8 * g4];
      const __bf16* f2 = fbase + (size_t)(144 + c * 18 + ks) * 512;
#pragma unroll
      for (int t = 0; t < 6; ++t) {
        bf16x8 bb = *(const bf16x8*)(f2 + (size_t)t * 3 * 512);
        acc[t] = __builtin_amdgcn_mfma_f32_16x16x32_bf16(pa, bb, acc[t], 0, 0, 0);
      }
    }
  }
  // epilogue: residual, in place (rows owned by this wave only)
#pragma unroll
  for (int r = 0; r < 4; ++r) {
    const size_t gr = (rowg + rowb + 4 * g4 + r) * 96;
#pragma unroll
    for (int t = 0; t < 6; ++t) {
      const size_t gi = gr + t * 16 + l15;
      xm[gi] = xm[gi] + acc[t][r];
    }
  }
}

extern "C" void kernel_launch(void* const* d_in, const int* in_sizes, int n_in,
                              void* d_out, int out_size, void* d_ws, size_t ws_size,
                              hipStream_t stream) {
  (void)in_sizes; (void)n_in; (void)out_size; (void)ws_size;
  const float* x     = (const float*)d_in[0];
  const float* ln1g  = (const float*)d_in[1];
  const float* ln1b  = (const float*)d_in[2];
  const float* qkvw  = (const float*)d_in[3];
  const float* qkvb  = (const float*)d_in[4];
  const float* projw = (const float*)d_in[5];
  const float* btab  = (const float*)d_in[6];
  const float* ln2g  = (const float*)d_in[7];
  const float* ln2b  = (const float*)d_in[8];
  const float* w1    = (const float*)d_in[9];
  const float* w2    = (const float*)d_in[10];
  float* out = (float*)d_out;
  __bf16* ws = (__bf16*)d_ws;

  // 122880 items = 110592 weight elems + 12288 bias elems
  swin_prep_kernel<<<480, 256, 0, stream>>>(qkvw, projw, w1, w2, btab, ws);
  swin_attn_kernel<<<4096, 256, 0, stream>>>(x, ln1g, ln1b, ws, qkvb, out);
  swin_mlp_kernel<<<4096, 256, 0, stream>>>(ln2g, ln2b, ws, out);
}